// Round 10
// baseline (651.991 us; speedup 1.0000x reference)
//
#include <hip/hip_runtime.h>
#include <hip/hip_bf16.h>
#include <cstdint>
#include <cstddef>

// ---------------------------------------------------------------------------
// ImprovedCrossScaleGNN on MI355X (gfx950).
// Inputs float32 + int32, output float32. bf16 MFMA GEMMs, f32 stats.
// R9->R10: MHA attention computed fully in registers (MFMA C-layout gives
// each lane 4 seq-rows x 1 feature col; dot-over-head = butterfly over the
// 16 r-lanes). Deletes q/k/v LDS staging (23->8.8 KB), one barrier, and all
// qkv bf16 round-trips. Rest unchanged from R9.
// ---------------------------------------------------------------------------

typedef __attribute__((ext_vector_type(8))) short bf16x8;
typedef __attribute__((ext_vector_type(4))) float f32x4;

#define EPSV 1e-5f

__device__ __forceinline__ float b2f(unsigned short u) {
    union { unsigned int i; float f; } x; x.i = ((unsigned int)u) << 16; return x.f;
}
__device__ __forceinline__ unsigned short f2b(float f) {
    union { float f; unsigned int i; } x; x.f = f;
    unsigned int i = x.i;
    return (unsigned short)((i + 0x7fffu + ((i >> 16) & 1u)) >> 16);
}

// ---------------- prep: all weight transposes/casts + feature casts ----------
__global__ void prep_kernel(const float* __restrict__ node_W, const float* __restrict__ comm_W,
                            const float* __restrict__ cls_W1, const float* __restrict__ attn_in_w,
                            const float* __restrict__ attn_out_w, const float* __restrict__ comm_feat,
                            const float* __restrict__ node_feat,
                            unsigned short* __restrict__ WtN, unsigned short* __restrict__ WtC,
                            unsigned short* __restrict__ W1t, unsigned short* __restrict__ WinB,
                            unsigned short* __restrict__ WoutB, unsigned short* __restrict__ cfb,
                            unsigned short* __restrict__ nfb, int nC128, int nN128) {
    int idx = blockIdx.x * 256 + threadIdx.x;
    if (idx < 49152) {
        int l = idx >> 14, rem = idx & 16383, k = rem >> 7, c = rem & 127;
        WtN[(l << 14) + (c << 7) + k] = f2b(node_W[idx]); return;
    }
    idx -= 49152;
    if (idx < 49152) {
        int l = idx >> 14, rem = idx & 16383, k = rem >> 7, c = rem & 127;
        WtC[(l << 14) + (c << 7) + k] = f2b(comm_W[idx]); return;
    }
    idx -= 49152;
    if (idx < 8192) {
        int k = idx >> 6, c = idx & 63;
        W1t[c * 128 + k] = f2b(cls_W1[idx]); return;
    }
    idx -= 8192;
    if (idx < 49152) { WinB[idx] = f2b(attn_in_w[idx]); return; }
    idx -= 49152;
    if (idx < 16384) { WoutB[idx] = f2b(attn_out_w[idx]); return; }
    idx -= 16384;
    if (idx < nC128) { cfb[idx] = f2b(comm_feat[idx]); return; }
    idx -= nC128;
    if (idx < nN128) { nfb[idx] = f2b(node_feat[idx]); }
}

// ---------------- CSR build (dual) ----------------
__global__ void count_dual(const int* __restrict__ nd, int* __restrict__ cnt_n, int nE,
                           const int* __restrict__ cd, int* __restrict__ cnt_c, int cE) {
    int t = blockIdx.x * 256 + threadIdx.x;
    if (t < nE) atomicAdd(&cnt_n[nd[t]], 1);
    else if (t - nE < cE) atomicAdd(&cnt_c[cd[t - nE]], 1);
}

__global__ void dinv_dual(const int* __restrict__ cnt_n, float* __restrict__ di_n, int nN,
                          const int* __restrict__ cnt_c, float* __restrict__ di_c, int nC) {
    int t = blockIdx.x * 256 + threadIdx.x;
    if (t < nN) di_n[t] = rsqrtf((float)cnt_n[t] + 1.0f);
    else if (t - nN < nC) di_c[t - nN] = rsqrtf((float)cnt_c[t - nN] + 1.0f);
}

// scans PADDED counts: ceil8(cnt)
__global__ void scan_block_dual(const int* __restrict__ cnt_n, int* __restrict__ rs_n,
                                int* __restrict__ bsum_n, int nN, int nbN,
                                const int* __restrict__ cnt_c, int* __restrict__ rs_c,
                                int* __restrict__ bsum_c, int nC) {
    __shared__ int tmp[2048];
    const int* cnt; int* excl; int* bsum; int n, lb;
    if ((int)blockIdx.x < nbN) { cnt = cnt_n; excl = rs_n; bsum = bsum_n; n = nN; lb = blockIdx.x; }
    else { cnt = cnt_c; excl = rs_c; bsum = bsum_c; n = nC; lb = blockIdx.x - nbN; }
    int tid = threadIdx.x;
    int gid = lb * 1024 + tid;
    int v = (gid < n) ? ((cnt[gid] + 7) & ~7) : 0;
    int buf = 0;
    tmp[tid] = v;
    __syncthreads();
    for (int d = 1; d < 1024; d <<= 1) {
        int t = tmp[buf * 1024 + tid];
        int add = (tid >= d) ? tmp[buf * 1024 + tid - d] : 0;
        tmp[(1 - buf) * 1024 + tid] = t + add;
        buf = 1 - buf;
        __syncthreads();
    }
    int inc = tmp[buf * 1024 + tid];
    if (gid < n) excl[gid] = inc - v;
    if (tid == 1023) bsum[lb] = inc;
}

__global__ void scan_sums_dual(int* __restrict__ bsum_n, int nbN,
                               int* __restrict__ bsum_c, int nbC) {
    if (threadIdx.x == 0) {
        int acc = 0;
        for (int i = 0; i < nbN; ++i) { int t = bsum_n[i]; bsum_n[i] = acc; acc += t; }
    } else if (threadIdx.x == 1) {
        int acc = 0;
        for (int i = 0; i < nbC; ++i) { int t = bsum_c[i]; bsum_c[i] = acc; acc += t; }
    }
}

__global__ void scan_add_dual(int* __restrict__ rs_n, const int* __restrict__ bsum_n, int nN,
                              int* __restrict__ rs_c, const int* __restrict__ bsum_c, int nC) {
    int gid = blockIdx.x * 256 + threadIdx.x;
    if (gid < nN) rs_n[gid] += bsum_n[gid >> 10];
    else {
        int g = gid - nN;
        if (g < nC) rs_c[g] += bsum_c[g >> 10];
    }
}

__global__ void fill_dual(const int* __restrict__ ns, const int* __restrict__ ndst,
                          const float* __restrict__ di_n, const int* __restrict__ rs_n,
                          int* __restrict__ cur_n, int* __restrict__ csrc_n,
                          float* __restrict__ cw_n, int nE,
                          const int* __restrict__ cs, const int* __restrict__ cdst,
                          const float* __restrict__ di_c, const int* __restrict__ rs_c,
                          int* __restrict__ cur_c, int* __restrict__ csrc_c,
                          float* __restrict__ cw_c, int cE) {
    int e = blockIdx.x * 256 + threadIdx.x;
    if (e < nE) {
        int s = ns[e], d = ndst[e];
        int pos = atomicAdd(&cur_n[d], 1);
        int slot = rs_n[d] + pos;
        csrc_n[slot] = s;
        cw_n[slot] = di_n[s] * di_n[d];
    } else if (e - nE < cE) {
        int ee = e - nE;
        int s = cs[ee], d = cdst[ee];
        int pos = atomicAdd(&cur_c[d], 1);
        int slot = rs_c[d] + pos;
        csrc_c[slot] = s;
        cw_c[slot] = di_c[s] * di_c[d];
    }
}

// ---------------- MFMA GEMM wave body: 16 rows x 128 cols, bf16 out ----------
__device__ __forceinline__ void gemm_wave_128(const unsigned short* __restrict__ A,
                                              const unsigned short* __restrict__ Bt,
                                              unsigned short* __restrict__ D,
                                              int M, int m0, int lane) {
    int r = lane & 15, q = lane >> 4;
    int arow = m0 + r; if (arow >= M) arow = M - 1;
    const unsigned short* ap = A + (size_t)arow * 128 + q * 8;
    bf16x8 afrag[4];
#pragma unroll
    for (int kc = 0; kc < 4; ++kc)
        afrag[kc] = *(const bf16x8*)(const void*)(ap + kc * 32);
#pragma unroll
    for (int n0 = 0; n0 < 128; n0 += 16) {
        const unsigned short* bp = Bt + (size_t)(n0 + r) * 128 + q * 8;
        f32x4 acc = {0.f, 0.f, 0.f, 0.f};
#pragma unroll
        for (int kc = 0; kc < 4; ++kc) {
            bf16x8 bfrag = *(const bf16x8*)(const void*)(bp + kc * 32);
            acc = __builtin_amdgcn_mfma_f32_16x16x32_bf16(afrag[kc], bfrag, acc, 0, 0, 0);
        }
#pragma unroll
        for (int t = 0; t < 4; ++t) {
            int row = m0 + q * 4 + t;
            if (row < M) D[(size_t)row * 128 + n0 + r] = f2b(acc[t]);
        }
    }
}

__global__ __launch_bounds__(256) void gemm_dual(
    const unsigned short* __restrict__ A0, const unsigned short* __restrict__ Bt0,
    unsigned short* __restrict__ D0, int M0, int blocksA,
    const unsigned short* __restrict__ A1, const unsigned short* __restrict__ Bt1,
    unsigned short* __restrict__ D1, int M1) {
    int blk = blockIdx.x;
    const unsigned short *A, *Bt; unsigned short* D; int M, lb;
    if (blk < blocksA) { A = A0; Bt = Bt0; D = D0; M = M0; lb = blk; }
    else { A = A1; Bt = Bt1; D = D1; M = M1; lb = blk - blocksA; }
    int m0 = (lb * 4 + (int)(threadIdx.x >> 6)) * 16;
    if (m0 >= M) return;
    gemm_wave_128(A, Bt, D, M, m0, threadIdx.x & 63);
}

// classifier GEMM (generic Ncol, f32 out, bias)
__global__ void gemm_kernel(const unsigned short* __restrict__ A,
                            const unsigned short* __restrict__ Bt,
                            const float* __restrict__ bias,
                            float* __restrict__ D, int M, int Ncol) {
    int wave = (blockIdx.x * blockDim.x + threadIdx.x) >> 6;
    int lane = threadIdx.x & 63;
    int m0 = wave * 16;
    if (m0 >= M) return;
    int r = lane & 15, q = lane >> 4;
    int arow = m0 + r; if (arow >= M) arow = M - 1;
    const unsigned short* ap = A + (size_t)arow * 128 + q * 8;
    bf16x8 afrag[4];
#pragma unroll
    for (int kc = 0; kc < 4; ++kc)
        afrag[kc] = *(const bf16x8*)(const void*)(ap + kc * 32);
    for (int n0 = 0; n0 < Ncol; n0 += 16) {
        const unsigned short* bp = Bt + (size_t)(n0 + r) * 128 + q * 8;
        f32x4 acc = {0.f, 0.f, 0.f, 0.f};
#pragma unroll
        for (int kc = 0; kc < 4; ++kc) {
            bf16x8 bfrag = *(const bf16x8*)(const void*)(bp + kc * 32);
            acc = __builtin_amdgcn_mfma_f32_16x16x32_bf16(afrag[kc], bfrag, acc, 0, 0, 0);
        }
        float bv = bias[n0 + r];
#pragma unroll
        for (int t = 0; t < 4; ++t) {
            int row = m0 + q * 4 + t;
            if (row < M) D[(size_t)row * Ncol + n0 + r] = acc[t] + bv;
        }
    }
}

// ---------------- gather (CSR, rows padded to x8), dual-branch ---------------
__global__ __launch_bounds__(256) void gather_dual(
    const unsigned short* __restrict__ m0, const int* __restrict__ rs0,
    const int* __restrict__ cnt0,
    const int* __restrict__ cs0, const float* __restrict__ cw0,
    const float* __restrict__ di0, const float* __restrict__ b0,
    float* __restrict__ agg0, int n0, int blocksA,
    const unsigned short* __restrict__ m1, const int* __restrict__ rs1,
    const int* __restrict__ cnt1,
    const int* __restrict__ cs1, const float* __restrict__ cw1,
    const float* __restrict__ di1, const float* __restrict__ b1,
    float* __restrict__ agg1, int n1) {
    int blk = blockIdx.x;
    const unsigned short* m; const int *rs, *cnt, *cs; const float *cw, *di, *bias;
    float *agg; int n, lb;
    if (blk < blocksA) { m = m0; rs = rs0; cnt = cnt0; cs = cs0; cw = cw0; di = di0; bias = b0; agg = agg0; n = n0; lb = blk; }
    else { m = m1; rs = rs1; cnt = cnt1; cs = cs1; cw = cw1; di = di1; bias = b1; agg = agg1; n = n1; lb = blk - blocksA; }
    int wib = threadIdx.x >> 6, lane = threadIdx.x & 63;
    int node = lb * 4 + wib;
    if (node >= n) return;
    int start = rs[node];
    int end = start + ((cnt[node] + 7) & ~7);
    float a0 = 0.f, a1 = 0.f;
    for (int i = start; i < end; i += 8) {
        int   s[8]; float w[8]; unsigned int v[8];
#pragma unroll
        for (int j = 0; j < 8; ++j) { s[j] = cs[i + j]; w[j] = cw[i + j]; }
#pragma unroll
        for (int j = 0; j < 8; ++j)
            v[j] = *(const unsigned int*)(m + (size_t)s[j] * 128 + 2 * lane);
#pragma unroll
        for (int j = 0; j < 8; ++j) {
            a0 += b2f((unsigned short)(v[j] & 0xffff)) * w[j];
            a1 += b2f((unsigned short)(v[j] >> 16)) * w[j];
        }
    }
    float d = di[node]; float wself = d * d;
    unsigned int v = *(const unsigned int*)(m + (size_t)node * 128 + 2 * lane);
    a0 += b2f((unsigned short)(v & 0xffff)) * wself + bias[2 * lane];
    a1 += b2f((unsigned short)(v >> 16)) * wself + bias[2 * lane + 1];
    float2 o; o.x = a0; o.y = a1;
    ((float2*)(agg + (size_t)node * 128))[lane] = o;
}

// ---------------- BN stats (streaming pass over agg), dual-branch ------------
__global__ __launch_bounds__(256) void stats_dual(
    const float* __restrict__ agg0, float* __restrict__ sums0, int n0, int blocksA,
    const float* __restrict__ agg1, float* __restrict__ sums1, int n1) {
    __shared__ float rsum[256], rsq[256];
    int blk = blockIdx.x;
    const float* agg; float* sums; int n, lb, nb;
    if (blk < blocksA) { agg = agg0; sums = sums0; n = n0; lb = blk; nb = blocksA; }
    else { agg = agg1; sums = sums1; n = n1; lb = blk - blocksA; nb = gridDim.x - blocksA; }
    int rpb = (n + nb - 1) / nb;
    int t = threadIdx.x;
    int f = t & 127, half = t >> 7;
    int r0 = lb * rpb, r1 = r0 + rpb; if (r1 > n) r1 = n;
    float s = 0.f, s2 = 0.f;
    for (int r = r0 + half; r < r1; r += 2) {
        float v = agg[(size_t)r * 128 + f];
        s += v; s2 += v * v;
    }
    rsum[t] = s; rsq[t] = s2;
    __syncthreads();
    if (t < 128) atomicAdd(&sums[t], rsum[t] + rsum[t + 128]);
    else atomicAdd(&sums[128 + f], rsq[f] + rsq[t]);
}

// ---------------- BN finalize+apply, dual-branch -----------------------------
__global__ __launch_bounds__(256) void apply_dual(
    const float* __restrict__ agg0, const float* __restrict__ sums0,
    const float* __restrict__ g0, const float* __restrict__ be0,
    unsigned short* __restrict__ hb0, int n0, int blocksA, int useRes,
    const float* __restrict__ agg1, const float* __restrict__ sums1,
    const float* __restrict__ g1, const float* __restrict__ be1,
    unsigned short* __restrict__ hb1, int n1) {
    __shared__ float sc[128], sh[128];
    int blk = blockIdx.x;
    const float *agg, *sums, *g, *be; unsigned short* hb; int n, lb;
    if (blk < blocksA) { agg = agg0; sums = sums0; g = g0; be = be0; hb = hb0; n = n0; lb = blk; }
    else { agg = agg1; sums = sums1; g = g1; be = be1; hb = hb1; n = n1; lb = blk - blocksA; }
    int t = threadIdx.x;
    if (t < 128) {
        float inv = 1.f / (float)n;
        float mean = sums[t] * inv;
        float var = sums[128 + t] * inv - mean * mean;
        float rstd = rsqrtf(var + EPSV);
        float s = g[t] * rstd;
        sc[t] = s;
        sh[t] = be[t] - mean * s;
    }
    __syncthreads();
    int base = lb * 1024 + t * 4;
    if (base < n * 128) {
        float4 a = *(const float4*)(agg + base);
        ushort4 h = *(const ushort4*)(hb + base);
        int f = base & 127;
        float v0 = fmaxf(a.x * sc[f] + sh[f], 0.f);
        float v1 = fmaxf(a.y * sc[f + 1] + sh[f + 1], 0.f);
        float v2 = fmaxf(a.z * sc[f + 2] + sh[f + 2], 0.f);
        float v3 = fmaxf(a.w * sc[f + 3] + sh[f + 3], 0.f);
        if (useRes) { v0 += b2f(h.x); v1 += b2f(h.y); v2 += b2f(h.z); v3 += b2f(h.w); }
        ushort4 o; o.x = f2b(v0); o.y = f2b(v1); o.z = f2b(v2); o.w = f2b(v3);
        *(ushort4*)(hb + base) = o;
    }
}

// ---------------- fused MHA + mean + residual + LayerNorm --------------------
// 256 threads = 4 waves; wave hg owns head-group hg (2 heads). Attention is
// fully in-register: MFMA C-layout gives lane (q,r) rows 4q..4q+3 (= nodes
// 2q,2q+1 both seqs) at feature col r; dot-over-head = butterfly over the
// 16 r-lanes. Only O round-trips LDS (C-layout -> A-layout for out-proj).
__global__ __launch_bounds__(256) void mha_fused_kernel(
    const unsigned short* __restrict__ hbn, const unsigned short* __restrict__ hbc,
    const int* __restrict__ map,
    const unsigned short* __restrict__ WinB, const float* __restrict__ bin,
    const unsigned short* __restrict__ WoutB, const float* __restrict__ bout,
    const float* __restrict__ lng, const float* __restrict__ lnb,
    unsigned short* __restrict__ hfin, int nN, int nC) {
    __shared__ unsigned short obf_s[16 * 144];
    __shared__ float att_s[8 * 132];

    int b = blockIdx.x;
    int hg = threadIdx.x >> 6;
    int lane = threadIdx.x & 63;
    int r = lane & 15, q = lane >> 4;

    // A-fragment: 16 interleaved rows (node, comm[map])
    int anode = b * 8 + (r >> 1);
    if (anode >= nN) anode = nN - 1;
    const unsigned short* arow;
    if (r & 1) {
        int c = map[anode]; c = c < 0 ? 0 : (c >= nC ? nC - 1 : c);
        arow = hbc + (size_t)c * 128;
    } else {
        arow = hbn + (size_t)anode * 128;
    }
    bf16x8 afrag[4];
#pragma unroll
    for (int kc = 0; kc < 4; ++kc)
        afrag[kc] = *(const bf16x8*)(const void*)(arow + q * 8 + kc * 32);

    // ---- phase A: q/k/v MFMA tiles for this wave's 2 heads, kept in regs ----
    f32x4 qa[2], ka[2], va[2];
#pragma unroll
    for (int p = 0; p < 3; ++p) {
#pragma unroll
        for (int c = 0; c < 2; ++c) {
            int n0 = p * 128 + hg * 32 + c * 16;
            const unsigned short* bp = WinB + (size_t)(n0 + r) * 128 + q * 8;
            f32x4 acc = {0.f, 0.f, 0.f, 0.f};
#pragma unroll
            for (int kc = 0; kc < 4; ++kc) {
                bf16x8 bfrag = *(const bf16x8*)(const void*)(bp + kc * 32);
                acc = __builtin_amdgcn_mfma_f32_16x16x32_bf16(afrag[kc], bfrag, acc, 0, 0, 0);
            }
            float bv = bin[n0 + r];
#pragma unroll
            for (int t = 0; t < 4; ++t) acc[t] += bv;
            if (p == 0) qa[c] = acc; else if (p == 1) ka[c] = acc; else va[c] = acc;
        }
    }

    // ---- phase B: in-register attention per head ----
#pragma unroll
    for (int c = 0; c < 2; ++c) {
        // node 2q (rows 4q,4q+1) and node 2q+1 (rows 4q+2,4q+3)
        float s00 = qa[c][0] * ka[c][0], s01 = qa[c][0] * ka[c][1];
        float s10 = qa[c][1] * ka[c][0], s11 = qa[c][1] * ka[c][1];
        float u00 = qa[c][2] * ka[c][2], u01 = qa[c][2] * ka[c][3];
        float u10 = qa[c][3] * ka[c][2], u11 = qa[c][3] * ka[c][3];
#pragma unroll
        for (int mku = 1; mku <= 8; mku <<= 1) {
            s00 += __shfl_xor(s00, mku); s01 += __shfl_xor(s01, mku);
            s10 += __shfl_xor(s10, mku); s11 += __shfl_xor(s11, mku);
            u00 += __shfl_xor(u00, mku); u01 += __shfl_xor(u01, mku);
            u10 += __shfl_xor(u10, mku); u11 += __shfl_xor(u11, mku);
        }
        s00 *= 0.25f; s01 *= 0.25f; s10 *= 0.25f; s11 *= 0.25f;
        u00 *= 0.25f; u01 *= 0.25f; u10 *= 0.25f; u11 *= 0.25f;
        float m0 = fmaxf(s00, s01), m1 = fmaxf(s10, s11);
        float m2 = fmaxf(u00, u01), m3 = fmaxf(u10, u11);
        float e00 = __expf(s00 - m0), e01 = __expf(s01 - m0);
        float e10 = __expf(s10 - m1), e11 = __expf(s11 - m1);
        float f00 = __expf(u00 - m2), f01 = __expf(u01 - m2);
        float f10 = __expf(u10 - m3), f11 = __expf(u11 - m3);
        float i0 = 1.f / (e00 + e01), i1 = 1.f / (e10 + e11);
        float i2 = 1.f / (f00 + f01), i3 = 1.f / (f10 + f11);
        float o0 = (e00 * va[c][0] + e01 * va[c][1]) * i0;  // node 2q,  seq0
        float o1 = (e10 * va[c][0] + e11 * va[c][1]) * i1;  // node 2q,  seq1
        float o2 = (f00 * va[c][2] + f01 * va[c][3]) * i2;  // node 2q+1,seq0
        float o3 = (f10 * va[c][2] + f11 * va[c][3]) * i3;  // node 2q+1,seq1
        int ocol = (hg * 2 + c) * 16 + r;
        obf_s[(q * 4 + 0) * 144 + ocol] = f2b(o0);
        obf_s[(q * 4 + 1) * 144 + ocol] = f2b(o1);
        obf_s[(q * 4 + 2) * 144 + ocol] = f2b(o2);
        obf_s[(q * 4 + 3) * 144 + ocol] = f2b(o3);
    }
    __syncthreads();

    // ---- phase C: out-proj; wave hg handles n0 tiles {2hg, 2hg+1} ----
    bf16x8 ofrag[4];
#pragma unroll
    for (int kc = 0; kc < 4; ++kc)
        ofrag[kc] = *(const bf16x8*)(const void*)(obf_s + r * 144 + q * 8 + kc * 32);
#pragma unroll
    for (int c = 0; c < 2; ++c) {
        int n0 = (hg * 2 + c) * 16;
        const unsigned short* bp = WoutB + (size_t)(n0 + r) * 128 + q * 8;
        f32x4 acc = {0.f, 0.f, 0.f, 0.f};
#pragma unroll
        for (int kc = 0; kc < 4; ++kc) {
            bf16x8 bfrag = *(const bf16x8*)(const void*)(bp + kc * 32);
            acc = __builtin_amdgcn_mfma_f32_16x16x32_bf16(ofrag[kc], bfrag, acc, 0, 0, 0);
        }
        float bv = bout[n0 + r];
        att_s[(q * 2 + 0) * 132 + n0 + r] = 0.5f * (acc[0] + acc[1]) + bv;
        att_s[(q * 2 + 1) * 132 + n0 + r] = 0.5f * (acc[2] + acc[3]) + bv;
    }
    __syncthreads();

    // ---- phase D: residual + LayerNorm (32 lanes per node, 4 cols each) ----
    {
        int nl = threadIdx.x >> 5;
        int j2 = threadIdx.x & 31;
        int gnode = b * 8 + nl; if (gnode >= nN) gnode = nN - 1;
        const unsigned short* hrow = hbn + (size_t)gnode * 128 + j2 * 4;
        float x[4]; float s = 0.f, s2 = 0.f;
#pragma unroll
        for (int i = 0; i < 4; ++i) {
            x[i] = att_s[nl * 132 + j2 * 4 + i] + b2f(hrow[i]);
            s += x[i]; s2 += x[i] * x[i];
        }
        s += __shfl_xor(s, 1);  s2 += __shfl_xor(s2, 1);
        s += __shfl_xor(s, 2);  s2 += __shfl_xor(s2, 2);
        s += __shfl_xor(s, 4);  s2 += __shfl_xor(s2, 4);
        s += __shfl_xor(s, 8);  s2 += __shfl_xor(s2, 8);
        s += __shfl_xor(s, 16); s2 += __shfl_xor(s2, 16);
        float mu = s * (1.f / 128.f);
        float var = s2 * (1.f / 128.f) - mu * mu;
        float rstd = rsqrtf(var + EPSV);
        ushort4 o;
        o.x = f2b((x[0] - mu) * rstd * lng[j2 * 4]     + lnb[j2 * 4]);
        o.y = f2b((x[1] - mu) * rstd * lng[j2 * 4 + 1] + lnb[j2 * 4 + 1]);
        o.z = f2b((x[2] - mu) * rstd * lng[j2 * 4 + 2] + lnb[j2 * 4 + 2]);
        o.w = f2b((x[3] - mu) * rstd * lng[j2 * 4 + 3] + lnb[j2 * 4 + 3]);
        *(ushort4*)(hfin + (size_t)gnode * 128 + j2 * 4) = o;
    }
}

// ---------------- classifier stats (F=64) ----------------
__global__ __launch_bounds__(256) void stats64_kernel(const float* __restrict__ z,
                                                      float* __restrict__ sums, int N) {
    __shared__ float ls[4][64], lsq[4][64];
    int f = threadIdx.x & 63, rg = threadIdx.x >> 6;
    int r0 = blockIdx.x * 64 + rg * 16;
    int r1 = r0 + 16; if (r1 > N) r1 = N;
    float s = 0.f, s2 = 0.f;
    for (int r = r0; r < r1; ++r) {
        float v = z[(size_t)r * 64 + f];
        s += v; s2 += v * v;
    }
    ls[rg][f] = s; lsq[rg][f] = s2;
    __syncthreads();
    int t = threadIdx.x;
    if (t < 64) atomicAdd(&sums[t], ls[0][t] + ls[1][t] + ls[2][t] + ls[3][t]);
    else if (t < 128) { int c = t - 64; atomicAdd(&sums[64 + c], lsq[0][c] + lsq[1][c] + lsq[2][c] + lsq[3][c]); }
}

// ---------------- final: BN(inline finalize)+ReLU+Linear(64,10)+log_softmax --
__global__ __launch_bounds__(256) void final_kernel(const float* __restrict__ z,
                                                    const float* __restrict__ sums,
                                                    const float* __restrict__ g,
                                                    const float* __restrict__ be,
                                                    const float* __restrict__ W2,
                                                    const float* __restrict__ b2v,
                                                    float* __restrict__ out, int nN) {
    int node = blockIdx.x * 4 + (threadIdx.x >> 6);
    int lane = threadIdx.x & 63;
    float inv = 1.f / (float)nN;
    float mean = sums[lane] * inv;
    float var = sums[64 + lane] * inv - mean * mean;
    float sc = g[lane] * rsqrtf(var + EPSV);
    float sh = be[lane] - mean * sc;
    float v = 0.f;
    if (node < nN) v = fmaxf(z[(size_t)node * 64 + lane] * sc + sh, 0.f);
    float p[10];
    const float* wrow = W2 + lane * 10;
#pragma unroll
    for (int c = 0; c < 10; ++c) p[c] = v * wrow[c];
#pragma unroll
    for (int off = 32; off >= 1; off >>= 1) {
#pragma unroll
        for (int c = 0; c < 10; ++c) p[c] += __shfl_xor(p[c], off);
    }
    if (node >= nN) return;
    float l[10], mx = -1e30f;
#pragma unroll
    for (int c = 0; c < 10; ++c) { l[c] = p[c] + b2v[c]; mx = fmaxf(mx, l[c]); }
    float se = 0.f;
#pragma unroll
    for (int c = 0; c < 10; ++c) se += expf(l[c] - mx);
    float lse = mx + logf(se);
    if (lane < 10) out[(size_t)node * 10 + lane] = l[lane] - lse;
}

// ---------------------------------------------------------------------------
static inline int cdiv(long a, long b) { return (int)((a + b - 1) / b); }

extern "C" void kernel_launch(void* const* d_in, const int* in_sizes, int n_in,
                              void* d_out, int out_size, void* d_ws, size_t ws_size,
                              hipStream_t stream) {
    const float* node_feat = (const float*)d_in[0];
    const int*   nedge     = (const int*)d_in[1];
    const float* comm_feat = (const float*)d_in[2];
    const int*   cedge     = (const int*)d_in[3];
    const int*   n2c       = (const int*)d_in[4];
    const float* node_W    = (const float*)d_in[5];
    const float* node_b    = (const float*)d_in[6];
    const float* node_g    = (const float*)d_in[7];
    const float* node_beta = (const float*)d_in[8];
    const float* comm_W    = (const float*)d_in[9];
    const float* comm_b    = (const float*)d_in[10];
    const float* comm_g    = (const float*)d_in[11];
    const float* comm_beta = (const float*)d_in[12];
    const float* attn_in_w = (const float*)d_in[13];
    const float* attn_in_b = (const float*)d_in[14];
    const float* attn_out_w= (const float*)d_in[15];
    const float* attn_out_b= (const float*)d_in[16];
    const float* ln_g      = (const float*)d_in[17];
    const float* ln_b      = (const float*)d_in[18];
    const float* cls_W1    = (const float*)d_in[19];
    const float* cls_b1    = (const float*)d_in[20];
    const float* cls_bn_g  = (const float*)d_in[21];
    const float* cls_bn_b  = (const float*)d_in[22];
    const float* cls_W2    = (const float*)d_in[23];
    const float* cls_b2    = (const float*)d_in[24];

    const int nN = in_sizes[0] / 128;
    const int nE = in_sizes[1] / 2;
    const int nC = in_sizes[2] / 128;
    const int cE = in_sizes[3] / 2;
    const int padE_n = nE + 8 * nN;
    const int padE_c = cE + 8 * nC;

    char* ws = (char*)d_ws;
    size_t off = 0;
    auto alloc = [&](size_t bytes) -> char* {
        char* p = ws + off;
        off = (off + bytes + 255) & ~(size_t)255;
        return p;
    };
    // ---- contiguous zero region (single memset) ----
    size_t zero_begin = off;
    int*   cnt_n  = (int*)alloc((size_t)nN * 4);
    int*   cur_n  = (int*)alloc((size_t)nN * 4);
    int*   cnt_c  = (int*)alloc((size_t)nC * 4);
    int*   cur_c  = (int*)alloc((size_t)nC * 4);
    float* gsums  = (float*)alloc((size_t)6 * 256 * 4);
    float* csums  = (float*)alloc(128 * 4);
    int*   csrc_n = (int*)alloc((size_t)padE_n * 4);
    float* cw_n   = (float*)alloc((size_t)padE_n * 4);
    int*   csrc_c = (int*)alloc((size_t)padE_c * 4);
    float* cw_c   = (float*)alloc((size_t)padE_c * 4);
    size_t zero_bytes = off - zero_begin;
    // ---- CSR aux ----
    int*   rs_n   = (int*)alloc((size_t)(nN + 1) * 4);
    int*   bsum_n = (int*)alloc(256 * 4);
    float* dinv_n = (float*)alloc((size_t)nN * 4);
    int*   rs_c   = (int*)alloc((size_t)(nC + 1) * 4);
    int*   bsum_c = (int*)alloc(256 * 4);
    float* dinv_c = (float*)alloc((size_t)nC * 4);
    // ---- activations / weights ----
    unsigned short* hb_n  = (unsigned short*)alloc((size_t)nN * 256);
    unsigned short* hb_c  = (unsigned short*)alloc((size_t)nC * 256);
    unsigned short* cfb   = (unsigned short*)alloc((size_t)nC * 256);
    unsigned short* m_cb  = (unsigned short*)alloc((size_t)nC * 256);
    float*          agg_c = (float*)alloc((size_t)nC * 512);
    unsigned short* WtN  = (unsigned short*)alloc((size_t)3 * 16384 * 2);
    unsigned short* WtC  = (unsigned short*)alloc((size_t)3 * 16384 * 2);
    unsigned short* W1t  = (unsigned short*)alloc((size_t)64 * 128 * 2);
    unsigned short* WinB = (unsigned short*)alloc((size_t)384 * 128 * 2);
    unsigned short* WoutB= (unsigned short*)alloc((size_t)128 * 128 * 2);
    unsigned short* m_nb = (unsigned short*)alloc((size_t)nN * 256);
    float*          agg_n= (float*)alloc((size_t)nN * 512);
    // aliases (disjoint liveness)
    unsigned short* nfb  = (unsigned short*)agg_n;
    unsigned short* hfin = m_nb;
    float*          z    = agg_n;

    hipMemsetAsync(ws + zero_begin, 0, zero_bytes, stream);

    // ---- prep ----
    long prepN = 49152L * 3 + 8192 + 16384 + (long)nC * 128 + (long)nN * 128;
    prep_kernel<<<cdiv(prepN, 256), 256, 0, stream>>>(
        node_W, comm_W, cls_W1, attn_in_w, attn_out_w, comm_feat, node_feat,
        WtN, WtC, W1t, WinB, WoutB, cfb, nfb, nC * 128, nN * 128);

    // ---- CSR build (rows padded to x8) ----
    count_dual<<<cdiv((long)nE + cE, 256), 256, 0, stream>>>(nedge + nE, cnt_n, nE, cedge + cE, cnt_c, cE);
    dinv_dual<<<cdiv((long)nN + nC, 256), 256, 0, stream>>>(cnt_n, dinv_n, nN, cnt_c, dinv_c, nC);
    int nbN = cdiv(nN, 1024), nbC = cdiv(nC, 1024);
    scan_block_dual<<<nbN + nbC, 1024, 0, stream>>>(cnt_n, rs_n, bsum_n, nN, nbN, cnt_c, rs_c, bsum_c, nC);
    scan_sums_dual<<<1, 64, 0, stream>>>(bsum_n, nbN, bsum_c, nbC);
    scan_add_dual<<<cdiv((long)nN + nC, 256), 256, 0, stream>>>(rs_n, bsum_n, nN, rs_c, bsum_c, nC);
    fill_dual<<<cdiv((long)nE + cE, 256), 256, 0, stream>>>(
        nedge, nedge + nE, dinv_n, rs_n, cur_n, csrc_n, cw_n, nE,
        cedge, cedge + cE, dinv_c, rs_c, cur_c, csrc_c, cw_c, cE);

    // ---- GCN layers ----
    int gemmA = cdiv(nN, 64), gemmB = cdiv(nC, 64);
    int gatA = cdiv(nN, 4), gatB = cdiv(nC, 4);
    int appA = cdiv((long)nN * 128, 1024), appB = cdiv((long)nC * 128, 1024);
    for (int i = 0; i < 3; ++i) {
        const unsigned short* A0 = i == 0 ? nfb : hb_n;
        const unsigned short* A1 = i == 0 ? cfb : hb_c;
        float* s0 = gsums + (size_t)(i * 2 + 0) * 256;
        float* s1 = gsums + (size_t)(i * 2 + 1) * 256;
        gemm_dual<<<gemmA + gemmB, 256, 0, stream>>>(
            A0, WtN + i * 16384, m_nb, nN, gemmA,
            A1, WtC + i * 16384, m_cb, nC);
        gather_dual<<<gatA + gatB, 256, 0, stream>>>(
            m_nb, rs_n, cnt_n, csrc_n, cw_n, dinv_n, node_b + i * 128, agg_n, nN, gatA,
            m_cb, rs_c, cnt_c, csrc_c, cw_c, dinv_c, comm_b + i * 128, agg_c, nC);
        stats_dual<<<256 + 4, 256, 0, stream>>>(agg_n, s0, nN, 256, agg_c, s1, nC);
        apply_dual<<<appA + appB, 256, 0, stream>>>(
            agg_n, s0, node_g + i * 128, node_beta + i * 128, hb_n, nN, appA, i > 0 ? 1 : 0,
            agg_c, s1, comm_g + i * 128, comm_beta + i * 128, hb_c, nC);
    }

    // ---- fused MHA + mean + residual + LN ----
    mha_fused_kernel<<<cdiv(nN, 8), 256, 0, stream>>>(
        hb_n, hb_c, n2c, WinB, attn_in_b, WoutB, attn_out_b, ln_g, ln_b, hfin, nN, nC);

    // ---- classifier ----
    int waves1 = (nN + 15) / 16;
    gemm_kernel<<<cdiv((long)waves1 * 64, 256), 256, 0, stream>>>(
        hfin, W1t, cls_b1, z, nN, 64);
    stats64_kernel<<<cdiv(nN, 64), 256, 0, stream>>>(z, csums, nN);
    final_kernel<<<cdiv(nN, 4), 256, 0, stream>>>(z, csums, cls_bn_g, cls_bn_b,
                                                  cls_W2, cls_b2, (float*)d_out, nN);
}

// Round 11
// 543.669 us; speedup vs baseline: 1.1992x; 1.1992x over previous
//
#include <hip/hip_runtime.h>
#include <hip/hip_bf16.h>
#include <cstdint>
#include <cstddef>

// ---------------------------------------------------------------------------
// ImprovedCrossScaleGNN on MI355X (gfx950).
// Inputs float32 + int32, output float32. bf16 MFMA GEMMs, f32 stats.
// R10->R11: FRAGMENT-LINEAR weight layout. R5/R7/R8/R10 MHA variants all
// ~115us -> shared cap, not in-kernel latency. Every B-frag load was a
// 16-way scattered 64B gather ((n0+r)*128+q*8) thrashing L1. Weights are
// now stored in MFMA fragment order (tile,kc,lane -> 8 contiguous bf16):
// each kc load = one coalesced 1KB burst. Applied to all GEMM consumers.
// ---------------------------------------------------------------------------

typedef __attribute__((ext_vector_type(8))) short bf16x8;
typedef __attribute__((ext_vector_type(4))) float f32x4;

#define EPSV 1e-5f

__device__ __forceinline__ float b2f(unsigned short u) {
    union { unsigned int i; float f; } x; x.i = ((unsigned int)u) << 16; return x.f;
}
__device__ __forceinline__ unsigned short f2b(float f) {
    union { float f; unsigned int i; } x; x.f = f;
    unsigned int i = x.i;
    return (unsigned short)((i + 0x7fffu + ((i >> 16) & 1u)) >> 16);
}

// ---------------- prep: weights -> fragment-linear bf16 + feature casts ------
// Fragment order: out[((tile*4+kc)*64+lane)*8+j] = W[k][col],
// col = tile*16 + (lane&15), k = (lane>>4)*8 + kc*32 + j.
__global__ void prep_kernel(const float* __restrict__ node_W, const float* __restrict__ comm_W,
                            const float* __restrict__ cls_W1, const float* __restrict__ attn_in_w,
                            const float* __restrict__ attn_out_w, const float* __restrict__ comm_feat,
                            const float* __restrict__ node_feat,
                            unsigned short* __restrict__ WtN, unsigned short* __restrict__ WtC,
                            unsigned short* __restrict__ W1t, unsigned short* __restrict__ WinB,
                            unsigned short* __restrict__ WoutB, unsigned short* __restrict__ cfb,
                            unsigned short* __restrict__ nfb, int nC128, int nN128) {
    int idx = blockIdx.x * 256 + threadIdx.x;
    if (idx < 49152) {  // node_W [3][128][128] (W[k][col])
        int l = idx >> 14, e = idx & 16383;
        int j = e & 7, lane = (e >> 3) & 63, kc = (e >> 9) & 3, t = e >> 11;
        int col = t * 16 + (lane & 15);
        int k = (lane >> 4) * 8 + kc * 32 + j;
        WtN[idx] = f2b(node_W[l * 16384 + k * 128 + col]); return;
    }
    idx -= 49152;
    if (idx < 49152) {  // comm_W
        int l = idx >> 14, e = idx & 16383;
        int j = e & 7, lane = (e >> 3) & 63, kc = (e >> 9) & 3, t = e >> 11;
        int col = t * 16 + (lane & 15);
        int k = (lane >> 4) * 8 + kc * 32 + j;
        WtC[idx] = f2b(comm_W[l * 16384 + k * 128 + col]); return;
    }
    idx -= 49152;
    if (idx < 8192) {   // cls_W1 [128][64] (W[k][col]), 4 tiles
        int e = idx;
        int j = e & 7, lane = (e >> 3) & 63, kc = (e >> 9) & 3, t = e >> 11;
        int col = t * 16 + (lane & 15);
        int k = (lane >> 4) * 8 + kc * 32 + j;
        W1t[idx] = f2b(cls_W1[k * 64 + col]); return;
    }
    idx -= 8192;
    if (idx < 49152) {  // attn_in_w [384][128] = Bt[col][k], 24 tiles
        int e = idx;
        int j = e & 7, lane = (e >> 3) & 63, kc = (e >> 9) & 3, t = e >> 11;
        int col = t * 16 + (lane & 15);
        int k = (lane >> 4) * 8 + kc * 32 + j;
        WinB[idx] = f2b(attn_in_w[col * 128 + k]); return;
    }
    idx -= 49152;
    if (idx < 16384) {  // attn_out_w [128][128] = Bt[col][k], 8 tiles
        int e = idx;
        int j = e & 7, lane = (e >> 3) & 63, kc = (e >> 9) & 3, t = e >> 11;
        int col = t * 16 + (lane & 15);
        int k = (lane >> 4) * 8 + kc * 32 + j;
        WoutB[idx] = f2b(attn_out_w[col * 128 + k]); return;
    }
    idx -= 16384;
    if (idx < nC128) { cfb[idx] = f2b(comm_feat[idx]); return; }
    idx -= nC128;
    if (idx < nN128) { nfb[idx] = f2b(node_feat[idx]); }
}

// ---------------- CSR build (dual) ----------------
__global__ void count_dual(const int* __restrict__ nd, int* __restrict__ cnt_n, int nE,
                           const int* __restrict__ cd, int* __restrict__ cnt_c, int cE) {
    int t = blockIdx.x * 256 + threadIdx.x;
    if (t < nE) atomicAdd(&cnt_n[nd[t]], 1);
    else if (t - nE < cE) atomicAdd(&cnt_c[cd[t - nE]], 1);
}

__global__ void dinv_dual(const int* __restrict__ cnt_n, float* __restrict__ di_n, int nN,
                          const int* __restrict__ cnt_c, float* __restrict__ di_c, int nC) {
    int t = blockIdx.x * 256 + threadIdx.x;
    if (t < nN) di_n[t] = rsqrtf((float)cnt_n[t] + 1.0f);
    else if (t - nN < nC) di_c[t - nN] = rsqrtf((float)cnt_c[t - nN] + 1.0f);
}

// scans PADDED counts: ceil8(cnt)
__global__ void scan_block_dual(const int* __restrict__ cnt_n, int* __restrict__ rs_n,
                                int* __restrict__ bsum_n, int nN, int nbN,
                                const int* __restrict__ cnt_c, int* __restrict__ rs_c,
                                int* __restrict__ bsum_c, int nC) {
    __shared__ int tmp[2048];
    const int* cnt; int* excl; int* bsum; int n, lb;
    if ((int)blockIdx.x < nbN) { cnt = cnt_n; excl = rs_n; bsum = bsum_n; n = nN; lb = blockIdx.x; }
    else { cnt = cnt_c; excl = rs_c; bsum = bsum_c; n = nC; lb = blockIdx.x - nbN; }
    int tid = threadIdx.x;
    int gid = lb * 1024 + tid;
    int v = (gid < n) ? ((cnt[gid] + 7) & ~7) : 0;
    int buf = 0;
    tmp[tid] = v;
    __syncthreads();
    for (int d = 1; d < 1024; d <<= 1) {
        int t = tmp[buf * 1024 + tid];
        int add = (tid >= d) ? tmp[buf * 1024 + tid - d] : 0;
        tmp[(1 - buf) * 1024 + tid] = t + add;
        buf = 1 - buf;
        __syncthreads();
    }
    int inc = tmp[buf * 1024 + tid];
    if (gid < n) excl[gid] = inc - v;
    if (tid == 1023) bsum[lb] = inc;
}

__global__ void scan_sums_dual(int* __restrict__ bsum_n, int nbN,
                               int* __restrict__ bsum_c, int nbC) {
    if (threadIdx.x == 0) {
        int acc = 0;
        for (int i = 0; i < nbN; ++i) { int t = bsum_n[i]; bsum_n[i] = acc; acc += t; }
    } else if (threadIdx.x == 1) {
        int acc = 0;
        for (int i = 0; i < nbC; ++i) { int t = bsum_c[i]; bsum_c[i] = acc; acc += t; }
    }
}

__global__ void scan_add_dual(int* __restrict__ rs_n, const int* __restrict__ bsum_n, int nN,
                              int* __restrict__ rs_c, const int* __restrict__ bsum_c, int nC) {
    int gid = blockIdx.x * 256 + threadIdx.x;
    if (gid < nN) rs_n[gid] += bsum_n[gid >> 10];
    else {
        int g = gid - nN;
        if (g < nC) rs_c[g] += bsum_c[g >> 10];
    }
}

__global__ void fill_dual(const int* __restrict__ ns, const int* __restrict__ ndst,
                          const float* __restrict__ di_n, const int* __restrict__ rs_n,
                          int* __restrict__ cur_n, int* __restrict__ csrc_n,
                          float* __restrict__ cw_n, int nE,
                          const int* __restrict__ cs, const int* __restrict__ cdst,
                          const float* __restrict__ di_c, const int* __restrict__ rs_c,
                          int* __restrict__ cur_c, int* __restrict__ csrc_c,
                          float* __restrict__ cw_c, int cE) {
    int e = blockIdx.x * 256 + threadIdx.x;
    if (e < nE) {
        int s = ns[e], d = ndst[e];
        int pos = atomicAdd(&cur_n[d], 1);
        int slot = rs_n[d] + pos;
        csrc_n[slot] = s;
        cw_n[slot] = di_n[s] * di_n[d];
    } else if (e - nE < cE) {
        int ee = e - nE;
        int s = cs[ee], d = cdst[ee];
        int pos = atomicAdd(&cur_c[d], 1);
        int slot = rs_c[d] + pos;
        csrc_c[slot] = s;
        cw_c[slot] = di_c[s] * di_c[d];
    }
}

// ---------------- MFMA GEMM wave body: 16 rows x 128 cols, bf16 out ----------
// Bt is fragment-linear: bfrag(tile,kc) at Bt + (tile*4+kc)*512 + lane*8.
__device__ __forceinline__ void gemm_wave_128(const unsigned short* __restrict__ A,
                                              const unsigned short* __restrict__ Bt,
                                              unsigned short* __restrict__ D,
                                              int M, int m0, int lane) {
    int r = lane & 15, q = lane >> 4;
    int arow = m0 + r; if (arow >= M) arow = M - 1;
    const unsigned short* ap = A + (size_t)arow * 128 + q * 8;
    bf16x8 afrag[4];
#pragma unroll
    for (int kc = 0; kc < 4; ++kc)
        afrag[kc] = *(const bf16x8*)(const void*)(ap + kc * 32);
#pragma unroll
    for (int tt = 0; tt < 8; ++tt) {
        f32x4 acc = {0.f, 0.f, 0.f, 0.f};
#pragma unroll
        for (int kc = 0; kc < 4; ++kc) {
            bf16x8 bfrag = *(const bf16x8*)(const void*)(Bt + (((size_t)tt * 4 + kc) << 9) + lane * 8);
            acc = __builtin_amdgcn_mfma_f32_16x16x32_bf16(afrag[kc], bfrag, acc, 0, 0, 0);
        }
        int n0 = tt * 16;
#pragma unroll
        for (int t = 0; t < 4; ++t) {
            int row = m0 + q * 4 + t;
            if (row < M) D[(size_t)row * 128 + n0 + r] = f2b(acc[t]);
        }
    }
}

__global__ __launch_bounds__(256) void gemm_dual(
    const unsigned short* __restrict__ A0, const unsigned short* __restrict__ Bt0,
    unsigned short* __restrict__ D0, int M0, int blocksA,
    const unsigned short* __restrict__ A1, const unsigned short* __restrict__ Bt1,
    unsigned short* __restrict__ D1, int M1) {
    int blk = blockIdx.x;
    const unsigned short *A, *Bt; unsigned short* D; int M, lb;
    if (blk < blocksA) { A = A0; Bt = Bt0; D = D0; M = M0; lb = blk; }
    else { A = A1; Bt = Bt1; D = D1; M = M1; lb = blk - blocksA; }
    int m0 = (lb * 4 + (int)(threadIdx.x >> 6)) * 16;
    if (m0 >= M) return;
    gemm_wave_128(A, Bt, D, M, m0, threadIdx.x & 63);
}

// classifier GEMM (generic Ncol, f32 out, bias); Bt fragment-linear
__global__ void gemm_kernel(const unsigned short* __restrict__ A,
                            const unsigned short* __restrict__ Bt,
                            const float* __restrict__ bias,
                            float* __restrict__ D, int M, int Ncol) {
    int wave = (blockIdx.x * blockDim.x + threadIdx.x) >> 6;
    int lane = threadIdx.x & 63;
    int m0 = wave * 16;
    if (m0 >= M) return;
    int r = lane & 15, q = lane >> 4;
    int arow = m0 + r; if (arow >= M) arow = M - 1;
    const unsigned short* ap = A + (size_t)arow * 128 + q * 8;
    bf16x8 afrag[4];
#pragma unroll
    for (int kc = 0; kc < 4; ++kc)
        afrag[kc] = *(const bf16x8*)(const void*)(ap + kc * 32);
    int ntiles = Ncol >> 4;
    for (int tt = 0; tt < ntiles; ++tt) {
        f32x4 acc = {0.f, 0.f, 0.f, 0.f};
#pragma unroll
        for (int kc = 0; kc < 4; ++kc) {
            bf16x8 bfrag = *(const bf16x8*)(const void*)(Bt + (((size_t)tt * 4 + kc) << 9) + lane * 8);
            acc = __builtin_amdgcn_mfma_f32_16x16x32_bf16(afrag[kc], bfrag, acc, 0, 0, 0);
        }
        int n0 = tt * 16;
        float bv = bias[n0 + r];
#pragma unroll
        for (int t = 0; t < 4; ++t) {
            int row = m0 + q * 4 + t;
            if (row < M) D[(size_t)row * Ncol + n0 + r] = acc[t] + bv;
        }
    }
}

// ---------------- gather (CSR, rows padded to x8), dual-branch ---------------
__global__ __launch_bounds__(256) void gather_dual(
    const unsigned short* __restrict__ m0, const int* __restrict__ rs0,
    const int* __restrict__ cnt0,
    const int* __restrict__ cs0, const float* __restrict__ cw0,
    const float* __restrict__ di0, const float* __restrict__ b0,
    float* __restrict__ agg0, int n0, int blocksA,
    const unsigned short* __restrict__ m1, const int* __restrict__ rs1,
    const int* __restrict__ cnt1,
    const int* __restrict__ cs1, const float* __restrict__ cw1,
    const float* __restrict__ di1, const float* __restrict__ b1,
    float* __restrict__ agg1, int n1) {
    int blk = blockIdx.x;
    const unsigned short* m; const int *rs, *cnt, *cs; const float *cw, *di, *bias;
    float *agg; int n, lb;
    if (blk < blocksA) { m = m0; rs = rs0; cnt = cnt0; cs = cs0; cw = cw0; di = di0; bias = b0; agg = agg0; n = n0; lb = blk; }
    else { m = m1; rs = rs1; cnt = cnt1; cs = cs1; cw = cw1; di = di1; bias = b1; agg = agg1; n = n1; lb = blk - blocksA; }
    int wib = threadIdx.x >> 6, lane = threadIdx.x & 63;
    int node = lb * 4 + wib;
    if (node >= n) return;
    int start = rs[node];
    int end = start + ((cnt[node] + 7) & ~7);
    float a0 = 0.f, a1 = 0.f;
    for (int i = start; i < end; i += 8) {
        int   s[8]; float w[8]; unsigned int v[8];
#pragma unroll
        for (int j = 0; j < 8; ++j) { s[j] = cs[i + j]; w[j] = cw[i + j]; }
#pragma unroll
        for (int j = 0; j < 8; ++j)
            v[j] = *(const unsigned int*)(m + (size_t)s[j] * 128 + 2 * lane);
#pragma unroll
        for (int j = 0; j < 8; ++j) {
            a0 += b2f((unsigned short)(v[j] & 0xffff)) * w[j];
            a1 += b2f((unsigned short)(v[j] >> 16)) * w[j];
        }
    }
    float d = di[node]; float wself = d * d;
    unsigned int v = *(const unsigned int*)(m + (size_t)node * 128 + 2 * lane);
    a0 += b2f((unsigned short)(v & 0xffff)) * wself + bias[2 * lane];
    a1 += b2f((unsigned short)(v >> 16)) * wself + bias[2 * lane + 1];
    float2 o; o.x = a0; o.y = a1;
    ((float2*)(agg + (size_t)node * 128))[lane] = o;
}

// ---------------- BN stats (streaming pass over agg), dual-branch ------------
__global__ __launch_bounds__(256) void stats_dual(
    const float* __restrict__ agg0, float* __restrict__ sums0, int n0, int blocksA,
    const float* __restrict__ agg1, float* __restrict__ sums1, int n1) {
    __shared__ float rsum[256], rsq[256];
    int blk = blockIdx.x;
    const float* agg; float* sums; int n, lb, nb;
    if (blk < blocksA) { agg = agg0; sums = sums0; n = n0; lb = blk; nb = blocksA; }
    else { agg = agg1; sums = sums1; n = n1; lb = blk - blocksA; nb = gridDim.x - blocksA; }
    int rpb = (n + nb - 1) / nb;
    int t = threadIdx.x;
    int f = t & 127, half = t >> 7;
    int r0 = lb * rpb, r1 = r0 + rpb; if (r1 > n) r1 = n;
    float s = 0.f, s2 = 0.f;
    for (int r = r0 + half; r < r1; r += 2) {
        float v = agg[(size_t)r * 128 + f];
        s += v; s2 += v * v;
    }
    rsum[t] = s; rsq[t] = s2;
    __syncthreads();
    if (t < 128) atomicAdd(&sums[t], rsum[t] + rsum[t + 128]);
    else atomicAdd(&sums[128 + f], rsq[f] + rsq[t]);
}

// ---------------- BN finalize+apply, dual-branch -----------------------------
__global__ __launch_bounds__(256) void apply_dual(
    const float* __restrict__ agg0, const float* __restrict__ sums0,
    const float* __restrict__ g0, const float* __restrict__ be0,
    unsigned short* __restrict__ hb0, int n0, int blocksA, int useRes,
    const float* __restrict__ agg1, const float* __restrict__ sums1,
    const float* __restrict__ g1, const float* __restrict__ be1,
    unsigned short* __restrict__ hb1, int n1) {
    __shared__ float sc[128], sh[128];
    int blk = blockIdx.x;
    const float *agg, *sums, *g, *be; unsigned short* hb; int n, lb;
    if (blk < blocksA) { agg = agg0; sums = sums0; g = g0; be = be0; hb = hb0; n = n0; lb = blk; }
    else { agg = agg1; sums = sums1; g = g1; be = be1; hb = hb1; n = n1; lb = blk - blocksA; }
    int t = threadIdx.x;
    if (t < 128) {
        float inv = 1.f / (float)n;
        float mean = sums[t] * inv;
        float var = sums[128 + t] * inv - mean * mean;
        float rstd = rsqrtf(var + EPSV);
        float s = g[t] * rstd;
        sc[t] = s;
        sh[t] = be[t] - mean * s;
    }
    __syncthreads();
    int base = lb * 1024 + t * 4;
    if (base < n * 128) {
        float4 a = *(const float4*)(agg + base);
        ushort4 h = *(const ushort4*)(hb + base);
        int f = base & 127;
        float v0 = fmaxf(a.x * sc[f] + sh[f], 0.f);
        float v1 = fmaxf(a.y * sc[f + 1] + sh[f + 1], 0.f);
        float v2 = fmaxf(a.z * sc[f + 2] + sh[f + 2], 0.f);
        float v3 = fmaxf(a.w * sc[f + 3] + sh[f + 3], 0.f);
        if (useRes) { v0 += b2f(h.x); v1 += b2f(h.y); v2 += b2f(h.z); v3 += b2f(h.w); }
        ushort4 o; o.x = f2b(v0); o.y = f2b(v1); o.z = f2b(v2); o.w = f2b(v3);
        *(ushort4*)(hb + base) = o;
    }
}

// ---------------- fused MHA + mean + residual + LayerNorm --------------------
// 256 threads = 4 waves; wave hg owns head-group hg (2 heads). In-register
// attention; weights fragment-linear (coalesced 1KB loads).
__global__ __launch_bounds__(256) void mha_fused_kernel(
    const unsigned short* __restrict__ hbn, const unsigned short* __restrict__ hbc,
    const int* __restrict__ map,
    const unsigned short* __restrict__ WinB, const float* __restrict__ bin,
    const unsigned short* __restrict__ WoutB, const float* __restrict__ bout,
    const float* __restrict__ lng, const float* __restrict__ lnb,
    unsigned short* __restrict__ hfin, int nN, int nC) {
    __shared__ unsigned short obf_s[16 * 144];
    __shared__ float att_s[8 * 132];

    int b = blockIdx.x;
    int hg = threadIdx.x >> 6;
    int lane = threadIdx.x & 63;
    int r = lane & 15, q = lane >> 4;

    // A-fragment: 16 interleaved rows (node, comm[map])
    int anode = b * 8 + (r >> 1);
    if (anode >= nN) anode = nN - 1;
    const unsigned short* arow;
    if (r & 1) {
        int c = map[anode]; c = c < 0 ? 0 : (c >= nC ? nC - 1 : c);
        arow = hbc + (size_t)c * 128;
    } else {
        arow = hbn + (size_t)anode * 128;
    }
    bf16x8 afrag[4];
#pragma unroll
    for (int kc = 0; kc < 4; ++kc)
        afrag[kc] = *(const bf16x8*)(const void*)(arow + q * 8 + kc * 32);

    // ---- phase A: q/k/v MFMA tiles for this wave's 2 heads, kept in regs ----
    f32x4 qa[2], ka[2], va[2];
#pragma unroll
    for (int p = 0; p < 3; ++p) {
#pragma unroll
        for (int c = 0; c < 2; ++c) {
            int tt = p * 8 + hg * 2 + c;      // tile index in WinB (24 tiles)
            f32x4 acc = {0.f, 0.f, 0.f, 0.f};
#pragma unroll
            for (int kc = 0; kc < 4; ++kc) {
                bf16x8 bfrag = *(const bf16x8*)(const void*)(WinB + (((size_t)tt * 4 + kc) << 9) + lane * 8);
                acc = __builtin_amdgcn_mfma_f32_16x16x32_bf16(afrag[kc], bfrag, acc, 0, 0, 0);
            }
            float bv = bin[tt * 16 + r];
#pragma unroll
            for (int t = 0; t < 4; ++t) acc[t] += bv;
            if (p == 0) qa[c] = acc; else if (p == 1) ka[c] = acc; else va[c] = acc;
        }
    }

    // ---- phase B: in-register attention per head ----
#pragma unroll
    for (int c = 0; c < 2; ++c) {
        float s00 = qa[c][0] * ka[c][0], s01 = qa[c][0] * ka[c][1];
        float s10 = qa[c][1] * ka[c][0], s11 = qa[c][1] * ka[c][1];
        float u00 = qa[c][2] * ka[c][2], u01 = qa[c][2] * ka[c][3];
        float u10 = qa[c][3] * ka[c][2], u11 = qa[c][3] * ka[c][3];
#pragma unroll
        for (int mku = 1; mku <= 8; mku <<= 1) {
            s00 += __shfl_xor(s00, mku); s01 += __shfl_xor(s01, mku);
            s10 += __shfl_xor(s10, mku); s11 += __shfl_xor(s11, mku);
            u00 += __shfl_xor(u00, mku); u01 += __shfl_xor(u01, mku);
            u10 += __shfl_xor(u10, mku); u11 += __shfl_xor(u11, mku);
        }
        s00 *= 0.25f; s01 *= 0.25f; s10 *= 0.25f; s11 *= 0.25f;
        u00 *= 0.25f; u01 *= 0.25f; u10 *= 0.25f; u11 *= 0.25f;
        float m0 = fmaxf(s00, s01), m1 = fmaxf(s10, s11);
        float m2 = fmaxf(u00, u01), m3 = fmaxf(u10, u11);
        float e00 = __expf(s00 - m0), e01 = __expf(s01 - m0);
        float e10 = __expf(s10 - m1), e11 = __expf(s11 - m1);
        float f00 = __expf(u00 - m2), f01 = __expf(u01 - m2);
        float f10 = __expf(u10 - m3), f11 = __expf(u11 - m3);
        float i0 = 1.f / (e00 + e01), i1 = 1.f / (e10 + e11);
        float i2 = 1.f / (f00 + f01), i3 = 1.f / (f10 + f11);
        float o0 = (e00 * va[c][0] + e01 * va[c][1]) * i0;
        float o1 = (e10 * va[c][0] + e11 * va[c][1]) * i1;
        float o2 = (f00 * va[c][2] + f01 * va[c][3]) * i2;
        float o3 = (f10 * va[c][2] + f11 * va[c][3]) * i3;
        int ocol = (hg * 2 + c) * 16 + r;
        obf_s[(q * 4 + 0) * 144 + ocol] = f2b(o0);
        obf_s[(q * 4 + 1) * 144 + ocol] = f2b(o1);
        obf_s[(q * 4 + 2) * 144 + ocol] = f2b(o2);
        obf_s[(q * 4 + 3) * 144 + ocol] = f2b(o3);
    }
    __syncthreads();

    // ---- phase C: out-proj; wave hg handles tiles {2hg, 2hg+1} ----
    bf16x8 ofrag[4];
#pragma unroll
    for (int kc = 0; kc < 4; ++kc)
        ofrag[kc] = *(const bf16x8*)(const void*)(obf_s + r * 144 + q * 8 + kc * 32);
#pragma unroll
    for (int c = 0; c < 2; ++c) {
        int tt = hg * 2 + c;
        f32x4 acc = {0.f, 0.f, 0.f, 0.f};
#pragma unroll
        for (int kc = 0; kc < 4; ++kc) {
            bf16x8 bfrag = *(const bf16x8*)(const void*)(WoutB + (((size_t)tt * 4 + kc) << 9) + lane * 8);
            acc = __builtin_amdgcn_mfma_f32_16x16x32_bf16(ofrag[kc], bfrag, acc, 0, 0, 0);
        }
        int n0 = tt * 16;
        float bv = bout[n0 + r];
        att_s[(q * 2 + 0) * 132 + n0 + r] = 0.5f * (acc[0] + acc[1]) + bv;
        att_s[(q * 2 + 1) * 132 + n0 + r] = 0.5f * (acc[2] + acc[3]) + bv;
    }
    __syncthreads();

    // ---- phase D: residual + LayerNorm (32 lanes per node, 4 cols each) ----
    {
        int nl = threadIdx.x >> 5;
        int j2 = threadIdx.x & 31;
        int gnode = b * 8 + nl; if (gnode >= nN) gnode = nN - 1;
        const unsigned short* hrow = hbn + (size_t)gnode * 128 + j2 * 4;
        float x[4]; float s = 0.f, s2 = 0.f;
#pragma unroll
        for (int i = 0; i < 4; ++i) {
            x[i] = att_s[nl * 132 + j2 * 4 + i] + b2f(hrow[i]);
            s += x[i]; s2 += x[i] * x[i];
        }
        s += __shfl_xor(s, 1);  s2 += __shfl_xor(s2, 1);
        s += __shfl_xor(s, 2);  s2 += __shfl_xor(s2, 2);
        s += __shfl_xor(s, 4);  s2 += __shfl_xor(s2, 4);
        s += __shfl_xor(s, 8);  s2 += __shfl_xor(s2, 8);
        s += __shfl_xor(s, 16); s2 += __shfl_xor(s2, 16);
        float mu = s * (1.f / 128.f);
        float var = s2 * (1.f / 128.f) - mu * mu;
        float rstd = rsqrtf(var + EPSV);
        ushort4 o;
        o.x = f2b((x[0] - mu) * rstd * lng[j2 * 4]     + lnb[j2 * 4]);
        o.y = f2b((x[1] - mu) * rstd * lng[j2 * 4 + 1] + lnb[j2 * 4 + 1]);
        o.z = f2b((x[2] - mu) * rstd * lng[j2 * 4 + 2] + lnb[j2 * 4 + 2]);
        o.w = f2b((x[3] - mu) * rstd * lng[j2 * 4 + 3] + lnb[j2 * 4 + 3]);
        *(ushort4*)(hfin + (size_t)gnode * 128 + j2 * 4) = o;
    }
}

// ---------------- classifier stats (F=64) ----------------
__global__ __launch_bounds__(256) void stats64_kernel(const float* __restrict__ z,
                                                      float* __restrict__ sums, int N) {
    __shared__ float ls[4][64], lsq[4][64];
    int f = threadIdx.x & 63, rg = threadIdx.x >> 6;
    int r0 = blockIdx.x * 64 + rg * 16;
    int r1 = r0 + 16; if (r1 > N) r1 = N;
    float s = 0.f, s2 = 0.f;
    for (int r = r0; r < r1; ++r) {
        float v = z[(size_t)r * 64 + f];
        s += v; s2 += v * v;
    }
    ls[rg][f] = s; lsq[rg][f] = s2;
    __syncthreads();
    int t = threadIdx.x;
    if (t < 64) atomicAdd(&sums[t], ls[0][t] + ls[1][t] + ls[2][t] + ls[3][t]);
    else if (t < 128) { int c = t - 64; atomicAdd(&sums[64 + c], lsq[0][c] + lsq[1][c] + lsq[2][c] + lsq[3][c]); }
}

// ---------------- final: BN(inline finalize)+ReLU+Linear(64,10)+log_softmax --
__global__ __launch_bounds__(256) void final_kernel(const float* __restrict__ z,
                                                    const float* __restrict__ sums,
                                                    const float* __restrict__ g,
                                                    const float* __restrict__ be,
                                                    const float* __restrict__ W2,
                                                    const float* __restrict__ b2v,
                                                    float* __restrict__ out, int nN) {
    int node = blockIdx.x * 4 + (threadIdx.x >> 6);
    int lane = threadIdx.x & 63;
    float inv = 1.f / (float)nN;
    float mean = sums[lane] * inv;
    float var = sums[64 + lane] * inv - mean * mean;
    float sc = g[lane] * rsqrtf(var + EPSV);
    float sh = be[lane] - mean * sc;
    float v = 0.f;
    if (node < nN) v = fmaxf(z[(size_t)node * 64 + lane] * sc + sh, 0.f);
    float p[10];
    const float* wrow = W2 + lane * 10;
#pragma unroll
    for (int c = 0; c < 10; ++c) p[c] = v * wrow[c];
#pragma unroll
    for (int off = 32; off >= 1; off >>= 1) {
#pragma unroll
        for (int c = 0; c < 10; ++c) p[c] += __shfl_xor(p[c], off);
    }
    if (node >= nN) return;
    float l[10], mx = -1e30f;
#pragma unroll
    for (int c = 0; c < 10; ++c) { l[c] = p[c] + b2v[c]; mx = fmaxf(mx, l[c]); }
    float se = 0.f;
#pragma unroll
    for (int c = 0; c < 10; ++c) se += expf(l[c] - mx);
    float lse = mx + logf(se);
    if (lane < 10) out[(size_t)node * 10 + lane] = l[lane] - lse;
}

// ---------------------------------------------------------------------------
static inline int cdiv(long a, long b) { return (int)((a + b - 1) / b); }

extern "C" void kernel_launch(void* const* d_in, const int* in_sizes, int n_in,
                              void* d_out, int out_size, void* d_ws, size_t ws_size,
                              hipStream_t stream) {
    const float* node_feat = (const float*)d_in[0];
    const int*   nedge     = (const int*)d_in[1];
    const float* comm_feat = (const float*)d_in[2];
    const int*   cedge     = (const int*)d_in[3];
    const int*   n2c       = (const int*)d_in[4];
    const float* node_W    = (const float*)d_in[5];
    const float* node_b    = (const float*)d_in[6];
    const float* node_g    = (const float*)d_in[7];
    const float* node_beta = (const float*)d_in[8];
    const float* comm_W    = (const float*)d_in[9];
    const float* comm_b    = (const float*)d_in[10];
    const float* comm_g    = (const float*)d_in[11];
    const float* comm_beta = (const float*)d_in[12];
    const float* attn_in_w = (const float*)d_in[13];
    const float* attn_in_b = (const float*)d_in[14];
    const float* attn_out_w= (const float*)d_in[15];
    const float* attn_out_b= (const float*)d_in[16];
    const float* ln_g      = (const float*)d_in[17];
    const float* ln_b      = (const float*)d_in[18];
    const float* cls_W1    = (const float*)d_in[19];
    const float* cls_b1    = (const float*)d_in[20];
    const float* cls_bn_g  = (const float*)d_in[21];
    const float* cls_bn_b  = (const float*)d_in[22];
    const float* cls_W2    = (const float*)d_in[23];
    const float* cls_b2    = (const float*)d_in[24];

    const int nN = in_sizes[0] / 128;
    const int nE = in_sizes[1] / 2;
    const int nC = in_sizes[2] / 128;
    const int cE = in_sizes[3] / 2;
    const int padE_n = nE + 8 * nN;
    const int padE_c = cE + 8 * nC;

    char* ws = (char*)d_ws;
    size_t off = 0;
    auto alloc = [&](size_t bytes) -> char* {
        char* p = ws + off;
        off = (off + bytes + 255) & ~(size_t)255;
        return p;
    };
    // ---- contiguous zero region (single memset) ----
    size_t zero_begin = off;
    int*   cnt_n  = (int*)alloc((size_t)nN * 4);
    int*   cur_n  = (int*)alloc((size_t)nN * 4);
    int*   cnt_c  = (int*)alloc((size_t)nC * 4);
    int*   cur_c  = (int*)alloc((size_t)nC * 4);
    float* gsums  = (float*)alloc((size_t)6 * 256 * 4);
    float* csums  = (float*)alloc(128 * 4);
    int*   csrc_n = (int*)alloc((size_t)padE_n * 4);
    float* cw_n   = (float*)alloc((size_t)padE_n * 4);
    int*   csrc_c = (int*)alloc((size_t)padE_c * 4);
    float* cw_c   = (float*)alloc((size_t)padE_c * 4);
    size_t zero_bytes = off - zero_begin;
    // ---- CSR aux ----
    int*   rs_n   = (int*)alloc((size_t)(nN + 1) * 4);
    int*   bsum_n = (int*)alloc(256 * 4);
    float* dinv_n = (float*)alloc((size_t)nN * 4);
    int*   rs_c   = (int*)alloc((size_t)(nC + 1) * 4);
    int*   bsum_c = (int*)alloc(256 * 4);
    float* dinv_c = (float*)alloc((size_t)nC * 4);
    // ---- activations / weights ----
    unsigned short* hb_n  = (unsigned short*)alloc((size_t)nN * 256);
    unsigned short* hb_c  = (unsigned short*)alloc((size_t)nC * 256);
    unsigned short* cfb   = (unsigned short*)alloc((size_t)nC * 256);
    unsigned short* m_cb  = (unsigned short*)alloc((size_t)nC * 256);
    float*          agg_c = (float*)alloc((size_t)nC * 512);
    unsigned short* WtN  = (unsigned short*)alloc((size_t)3 * 16384 * 2);
    unsigned short* WtC  = (unsigned short*)alloc((size_t)3 * 16384 * 2);
    unsigned short* W1t  = (unsigned short*)alloc((size_t)64 * 128 * 2);
    unsigned short* WinB = (unsigned short*)alloc((size_t)384 * 128 * 2);
    unsigned short* WoutB= (unsigned short*)alloc((size_t)128 * 128 * 2);
    unsigned short* m_nb = (unsigned short*)alloc((size_t)nN * 256);
    float*          agg_n= (float*)alloc((size_t)nN * 512);
    // aliases (disjoint liveness)
    unsigned short* nfb  = (unsigned short*)agg_n;
    unsigned short* hfin = m_nb;
    float*          z    = agg_n;

    hipMemsetAsync(ws + zero_begin, 0, zero_bytes, stream);

    // ---- prep ----
    long prepN = 49152L * 3 + 8192 + 16384 + (long)nC * 128 + (long)nN * 128;
    prep_kernel<<<cdiv(prepN, 256), 256, 0, stream>>>(
        node_W, comm_W, cls_W1, attn_in_w, attn_out_w, comm_feat, node_feat,
        WtN, WtC, W1t, WinB, WoutB, cfb, nfb, nC * 128, nN * 128);

    // ---- CSR build (rows padded to x8) ----
    count_dual<<<cdiv((long)nE + cE, 256), 256, 0, stream>>>(nedge + nE, cnt_n, nE, cedge + cE, cnt_c, cE);
    dinv_dual<<<cdiv((long)nN + nC, 256), 256, 0, stream>>>(cnt_n, dinv_n, nN, cnt_c, dinv_c, nC);
    int nbN = cdiv(nN, 1024), nbC = cdiv(nC, 1024);
    scan_block_dual<<<nbN + nbC, 1024, 0, stream>>>(cnt_n, rs_n, bsum_n, nN, nbN, cnt_c, rs_c, bsum_c, nC);
    scan_sums_dual<<<1, 64, 0, stream>>>(bsum_n, nbN, bsum_c, nbC);
    scan_add_dual<<<cdiv((long)nN + nC, 256), 256, 0, stream>>>(rs_n, bsum_n, nN, rs_c, bsum_c, nC);
    fill_dual<<<cdiv((long)nE + cE, 256), 256, 0, stream>>>(
        nedge, nedge + nE, dinv_n, rs_n, cur_n, csrc_n, cw_n, nE,
        cedge, cedge + cE, dinv_c, rs_c, cur_c, csrc_c, cw_c, cE);

    // ---- GCN layers ----
    int gemmA = cdiv(nN, 64), gemmB = cdiv(nC, 64);
    int gatA = cdiv(nN, 4), gatB = cdiv(nC, 4);
    int appA = cdiv((long)nN * 128, 1024), appB = cdiv((long)nC * 128, 1024);
    for (int i = 0; i < 3; ++i) {
        const unsigned short* A0 = i == 0 ? nfb : hb_n;
        const unsigned short* A1 = i == 0 ? cfb : hb_c;
        float* s0 = gsums + (size_t)(i * 2 + 0) * 256;
        float* s1 = gsums + (size_t)(i * 2 + 1) * 256;
        gemm_dual<<<gemmA + gemmB, 256, 0, stream>>>(
            A0, WtN + i * 16384, m_nb, nN, gemmA,
            A1, WtC + i * 16384, m_cb, nC);
        gather_dual<<<gatA + gatB, 256, 0, stream>>>(
            m_nb, rs_n, cnt_n, csrc_n, cw_n, dinv_n, node_b + i * 128, agg_n, nN, gatA,
            m_cb, rs_c, cnt_c, csrc_c, cw_c, dinv_c, comm_b + i * 128, agg_c, nC);
        stats_dual<<<256 + 4, 256, 0, stream>>>(agg_n, s0, nN, 256, agg_c, s1, nC);
        apply_dual<<<appA + appB, 256, 0, stream>>>(
            agg_n, s0, node_g + i * 128, node_beta + i * 128, hb_n, nN, appA, i > 0 ? 1 : 0,
            agg_c, s1, comm_g + i * 128, comm_beta + i * 128, hb_c, nC);
    }

    // ---- fused MHA + mean + residual + LN ----
    mha_fused_kernel<<<cdiv(nN, 8), 256, 0, stream>>>(
        hb_n, hb_c, n2c, WinB, attn_in_b, WoutB, attn_out_b, ln_g, ln_b, hfin, nN, nC);

    // ---- classifier ----
    int waves1 = (nN + 15) / 16;
    gemm_kernel<<<cdiv((long)waves1 * 64, 256), 256, 0, stream>>>(
        hfin, W1t, cls_b1, z, nN, 64);
    stats64_kernel<<<cdiv(nN, 64), 256, 0, stream>>>(z, csums, nN);
    final_kernel<<<cdiv(nN, 4), 256, 0, stream>>>(z, csums, cls_bn_g, cls_bn_b,
                                                  cls_W2, cls_b2, (float*)d_out, nN);
}